// Round 10
// baseline (326.193 us; speedup 1.0000x reference)
//
#include <hip/hip_runtime.h>
#include <math.h>

// Real grid (match reference): 421 x 421 E-grid, source at (210,210)
#define NXr 421
#define CXr 210
#define NSTEPS_C 200

// Round 10: wave-autonomous temporal tiles. Each 64-lane WAVE owns a 32x32
// tile (4x4 cells/lane, 8x8 lane grid) and advances Kt=8 steps with Ez
// exchanged through a wave-PRIVATE LDS buffer -- NO __syncthreads anywhere.
// Wave64 lockstep + in-order per-wave LDS pipe give write->read ordering;
// __builtin_amdgcn_wave_barrier() (zero-cost scheduling fence) stops the
// compiler reordering publish vs read; parity double-buffer kills the WAR.
// Block = 4 independent waves covering an owned 32x32 region; grid <= 14x14;
// 25 phases (200 = 25*8). R6/R8 showed the block-wide barrier critical path
// (~1 us/step at 1 block/CU) was the wall; this makes cp wave-local.
#define Kt   8
#define WEXT 32                    // wave tile edge
#define SP   36                    // LDS row pitch (mult of 4 -> b128 aligned)
#define NBLK 14                    // 14*32 = 448 >= 432 computational domain
#define NPHASE 25

// Padded zero-ring layout (verified R8/R9): fields PP x PP, domain at offset
// (PAD,PAD). Block b, wave (wi,wj): tile rows [32b+8+16wi, 32b+40+16wi),
// owned rows [32b+16+16wi, +16). Max padded row 472 < 480. Coefficient tables
// are zero outside the real 421^2 domain -> outside cells stay 0 forever ->
// all hot I/O unconditional float4. Guard row makes row/col -1 safe.
#define PP   480
#define PAD  16
#define CP   (CXr + PAD)           // source in padded coords: 226
#define FSZ  (PP * PP)

struct PParams {
    float *aEz, *aEo, *aJz, *aJo, *aHx, *aHy;   // state set A
    float *bEz, *bEo, *bJz, *bJo, *bHx, *bHy;   // state set B
    const float *dexP, *deyP, *aexP, *aeyP, *ahxP, *ahyP;  // padded 1-D tables
    const float *C1a, *C2a, *Cbdxa, *Cbdya;
    const float *Caa, *Cba, *Cca, *Cda, *Cea, *dbhxa, *dbhya;
    const float *src;
};

// ---------------------------------------------------------------------------
// Init: zero guard row + both padded state sets; build padded coeff tables.
// dexP/deyP fold the interior mask (nonzero only for real coords 1..419).
// Zeroing BOTH sets every call keeps the support-gating skip exact.
// ---------------------------------------------------------------------------
__global__ void init_kernel(const float* __restrict__ sig_ex,
                            const float* __restrict__ sig_ey,
                            const float* __restrict__ sig_hx,
                            const float* __restrict__ sig_hy,
                            float de_fac, float dh_fac,
                            float* __restrict__ zero_base, int n_zero,
                            float* __restrict__ dexP, float* __restrict__ deyP,
                            float* __restrict__ aexP, float* __restrict__ aeyP,
                            float* __restrict__ ahxP, float* __restrict__ ahyP)
{
    int t = blockIdx.x * blockDim.x + threadIdx.x;
    int stride = gridDim.x * blockDim.x;
    for (int k = t; k < n_zero; k += stride) zero_base[k] = 0.0f;
    if (t < PP) {
        int g = t - PAD;
        dexP[t] = (g >= 1 && g <= NXr - 2) ? expf(-sig_ex[g] * de_fac) : 0.0f;
        deyP[t] = (g >= 1 && g <= NXr - 2) ? expf(-sig_ey[g] * de_fac) : 0.0f;
        aexP[t] = (g >= 0 && g <  NXr)     ? expf(-sig_ex[g] * dh_fac) : 0.0f;
        aeyP[t] = (g >= 0 && g <  NXr)     ? expf(-sig_ey[g] * dh_fac) : 0.0f;
        ahxP[t] = (g >= 0 && g <  NXr - 1) ? expf(-sig_hx[g] * dh_fac) : 0.0f;
        ahyP[t] = (g >= 0 && g <  NXr - 1) ? expf(-sig_hy[g] * dh_fac) : 0.0f;
    }
}

// ---------------------------------------------------------------------------
// One temporal-blocked phase: 8 wave-local steps, zero block barriers.
// Per wave-tile validity: E-state valid [s, 32-s) at start of step s ->
// owned [8,24) exact after 8 steps (same induction as R6, per wave now).
// Up/left neighbor H kept as ghost registers updated redundantly from the
// exchanged Ez (identical arithmetic to the neighbor's own update).
// ---------------------------------------------------------------------------
__global__ __launch_bounds__(256, 1)
void phase_kernel(PParams p, int t, int b0, int n0)
{
    // 4 waves x 2 parity buffers x 32 rows x SP  = 36.9 KB
    __shared__ __align__(16) float sEz[4][2][WEXT][SP];

    const int tid = threadIdx.x;
    const int w  = tid >> 6;                 // wave index 0..3
    const int wi = w >> 1, wj = w & 1;       // wave quadrant in block
    const int l  = tid & 63;
    const int lr = l >> 3, lc = l & 7;       // 8x8 lane grid
    const int li0 = 4 * lr, lj0 = 4 * lc;    // cell origin within wave tile
    const int r0 = ((int)blockIdx.x + b0) * 32 + 8 + 16 * wi + li0;
    const int c0 = ((int)blockIdx.y + b0) * 32 + 8 + 16 * wj + lj0;

    const float ca = p.Caa[0], cb = p.Cba[0], cc = p.Cca[0];
    const float cd = p.Cda[0], ce = p.Cea[0];
    const float ca1 = ca + 1.0f;
    const float C1 = p.C1a[0], C2 = p.C2a[0];
    const float cbdx = p.Cbdxa[0], cbdy = p.Cbdya[0];
    const float dbhx0 = p.dbhxa[0], dbhy0 = p.dbhya[0];

    // 1-D row/col damping factors
    float aexr[4], ahxr[4], dexr[4], aeyc[4], ahyc[4], deyc[4];
#pragma unroll
    for (int a = 0; a < 4; ++a) {
        aexr[a] = p.aexP[r0 + a];
        ahxr[a] = p.ahxP[r0 + a];
        dexr[a] = p.dexP[r0 + a];
        aeyc[a] = p.aeyP[c0 + a];
        ahyc[a] = p.ahyP[c0 + a];
        deyc[a] = p.deyP[c0 + a];
    }
    const float ahxU = p.ahxP[r0 - 1];       // r0-1 >= 7: in-bounds
    const float ahyL = p.ahyP[c0 - 1];

    const bool odd = (t & 1) != 0;
    const float* cEz = odd ? p.bEz : p.aEz;
    const float* cEo = odd ? p.bEo : p.aEo;
    const float* cJz = odd ? p.bJz : p.aJz;
    const float* cJo = odd ? p.bJo : p.aJo;
    const float* cHx = odd ? p.bHx : p.aHx;
    const float* cHy = odd ? p.bHy : p.aHy;
    float* nEz = odd ? p.aEz : p.bEz;
    float* nEo = odd ? p.aEo : p.bEo;
    float* nJz = odd ? p.aJz : p.bJz;
    float* nJo = odd ? p.aJo : p.bJo;
    float* nHx = odd ? p.aHx : p.bHx;
    float* nHy = odd ? p.aHy : p.bHy;

    // Load 4x4 register state (unconditional padded float4; c0 % 4 == 0)
    float ez[4][4], eo[4][4], jz[4][4], jo[4][4], hx[4][4], hy[4][4];
#pragma unroll
    for (int a = 0; a < 4; ++a) {
        int g = (r0 + a) * PP + c0;
        float4 v;
        v = *(const float4*)&cEz[g]; ez[a][0]=v.x; ez[a][1]=v.y; ez[a][2]=v.z; ez[a][3]=v.w;
        v = *(const float4*)&cEo[g]; eo[a][0]=v.x; eo[a][1]=v.y; eo[a][2]=v.z; eo[a][3]=v.w;
        v = *(const float4*)&cJz[g]; jz[a][0]=v.x; jz[a][1]=v.y; jz[a][2]=v.z; jz[a][3]=v.w;
        v = *(const float4*)&cJo[g]; jo[a][0]=v.x; jo[a][1]=v.y; jo[a][2]=v.z; jo[a][3]=v.w;
        v = *(const float4*)&cHx[g]; hx[a][0]=v.x; hx[a][1]=v.y; hx[a][2]=v.z; hx[a][3]=v.w;
        v = *(const float4*)&cHy[g]; hy[a][0]=v.x; hy[a][1]=v.y; hy[a][2]=v.z; hy[a][3]=v.w;
    }
    // Ghost H (row above / col left of the quad); guard row / zero pad safe
    float hyU[4], hxL[4];
    {
        float4 v = *(const float4*)&cHy[(r0 - 1) * PP + c0];
        hyU[0]=v.x; hyU[1]=v.y; hyU[2]=v.z; hyU[3]=v.w;
#pragma unroll
        for (int a = 0; a < 4; ++a) hxL[a] = cHx[(r0 + a) * PP + c0 - 1];
    }

    // Preload the 8 source samples (uniform scalar loads, hoisted off the chain)
    float sv[Kt];
#pragma unroll
    for (int s = 0; s < Kt; ++s) sv[s] = p.src[n0 + s];

    const bool edgeR = (lc == 7), edgeD = (lr == 7);
    const bool edgeU = (lr == 0), edgeL = (lc == 0);

#pragma unroll
    for (int s = 0; s < Kt; ++s) {
        float (*S)[SP] = sEz[w][s & 1];
        // publish all 16 Ez cells into this wave's parity buffer
#pragma unroll
        for (int a = 0; a < 4; ++a)
            *(float4*)&S[li0 + a][lj0] =
                make_float4(ez[a][0], ez[a][1], ez[a][2], ez[a][3]);
        // Zero-cost scheduling fence: keeps the cross-lane reads below from
        // being hoisted above the writes. HW LDS pipe is in-order per wave,
        // so no execution barrier is needed (wave-synchronous idiom).
        __builtin_amdgcn_wave_barrier();

        float eR[4], eL[4];
#pragma unroll
        for (int a = 0; a < 4; ++a) {
            eR[a] = edgeR ? 0.0f : S[li0 + a][lj0 + 4];
            eL[a] = edgeL ? 0.0f : S[li0 + a][lj0 - 1];
        }
        float4 eD4 = edgeD ? make_float4(0.f,0.f,0.f,0.f)
                           : *(float4*)&S[li0 + 4][lj0];
        float4 eU4 = edgeU ? make_float4(0.f,0.f,0.f,0.f)
                           : *(float4*)&S[li0 - 1][lj0];
        float eD[4] = {eD4.x, eD4.y, eD4.z, eD4.w};
        float eU[4] = {eU4.x, eU4.y, eU4.z, eU4.w};
        // (No fence needed before the next step's publish: it targets the
        //  OTHER parity buffer, so there is no WAR on this one.)

        // ---- H update (own 4x4) ----
#pragma unroll
        for (int a = 0; a < 4; ++a) {
#pragma unroll
            for (int b = 0; b < 3; ++b)
                hx[a][b] = aexr[a] * ahyc[b] *
                           (hx[a][b] - dbhx0 * (ez[a][b + 1] - ez[a][b]));
            hx[a][3] = aexr[a] * ahyc[3] *
                       (hx[a][3] - dbhx0 * (eR[a] - ez[a][3]));
        }
#pragma unroll
        for (int b = 0; b < 4; ++b) {
#pragma unroll
            for (int a = 0; a < 3; ++a)
                hy[a][b] = ahxr[a] * aeyc[b] *
                           (hy[a][b] + dbhy0 * (ez[a + 1][b] - ez[a][b]));
            hy[3][b] = ahxr[3] * aeyc[b] *
                       (hy[3][b] + dbhy0 * (eD[b] - ez[3][b]));
        }

        // ---- ghost H update (same arithmetic as neighbor's own) ----
#pragma unroll
        for (int b = 0; b < 4; ++b)
            hyU[b] = ahxU * aeyc[b] * (hyU[b] + dbhy0 * (ez[0][b] - eU[b]));
#pragma unroll
        for (int a = 0; a < 4; ++a)
            hxL[a] = aexr[a] * ahyL * (hxL[a] - dbhx0 * (ez[a][0] - eL[a]));

        // ---- E update (all operands in registers) ----
#pragma unroll
        for (int a = 0; a < 4; ++a)
#pragma unroll
            for (int b = 0; b < 4; ++b) {
                float cHyv = hy[a][b] - (a ? hy[a - 1][b] : hyU[b]);
                float cHxv = hx[a][b] - (b ? hx[a][b - 1] : hxL[a]);
                float e = ez[a][b], eold = eo[a][b];
                float j = jz[a][b], jold = jo[a][b];
                float phi = ca1 * j + cb * jold + cd * e + ce * eold;
                float en = (dexr[a] * deyc[b]) *
                    (C1 * e + cbdx * cHyv - cbdy * cHxv - C2 * phi);
                if (r0 + a == CP && c0 + b == CP) en += sv[s];
                float jn = phi - j + cc * en;   // == ca*j+cb*jo+cc*en+cd*e+ce*eo
                eo[a][b] = e;  ez[a][b] = en;
                jo[a][b] = j;  jz[a][b] = jn;
            }
    }

    // store owned interior: tile cells li,lj in [8,24) -> lanes lr,lc in [2,6)
    if (lr >= 2 && lr < 6 && lc >= 2 && lc < 6) {
#pragma unroll
        for (int a = 0; a < 4; ++a) {
            int g = (r0 + a) * PP + c0;
            *(float4*)&nEz[g] = make_float4(ez[a][0], ez[a][1], ez[a][2], ez[a][3]);
            *(float4*)&nEo[g] = make_float4(eo[a][0], eo[a][1], eo[a][2], eo[a][3]);
            *(float4*)&nJz[g] = make_float4(jz[a][0], jz[a][1], jz[a][2], jz[a][3]);
            *(float4*)&nJo[g] = make_float4(jo[a][0], jo[a][1], jo[a][2], jo[a][3]);
            *(float4*)&nHx[g] = make_float4(hx[a][0], hx[a][1], hx[a][2], hx[a][3]);
            *(float4*)&nHy[g] = make_float4(hy[a][0], hy[a][1], hy[a][2], hy[a][3]);
        }
    }
}

// ---------------------------------------------------------------------------
// Copy padded Ez -> dense 421x421 output.
// ---------------------------------------------------------------------------
__global__ void copy_out_kernel(const float* __restrict__ ezP,
                                float* __restrict__ out)
{
    int idx = blockIdx.x * blockDim.x + threadIdx.x;
    if (idx >= NXr * NXr) return;
    int gi = idx / NXr, gj = idx - gi * NXr;
    out[idx] = ezP[(gi + PAD) * PP + (gj + PAD)];
}

// ---------------------------------------------------------------------------
extern "C" void kernel_launch(void* const* d_in, const int* in_sizes, int n_in,
                              void* d_out, int out_size, void* d_ws, size_t ws_size,
                              hipStream_t stream)
{
    const float* src    = (const float*)d_in[0];
    const float* C1     = (const float*)d_in[1];
    const float* C2     = (const float*)d_in[2];
    const float* Cb_dx  = (const float*)d_in[3];
    const float* Cb_dy  = (const float*)d_in[4];
    const float* dbhx   = (const float*)d_in[5];
    const float* dbhy   = (const float*)d_in[6];
    const float* Ca     = (const float*)d_in[7];
    const float* Cb     = (const float*)d_in[8];
    const float* Cc     = (const float*)d_in[9];
    const float* Cd     = (const float*)d_in[10];
    const float* Ce     = (const float*)d_in[11];
    const float* sig_ex = (const float*)d_in[12];
    const float* sig_ey = (const float*)d_in[13];
    const float* sig_hx = (const float*)d_in[14];
    const float* sig_hy = (const float*)d_in[15];
    // d_in[16] = n_steps (always 200) — hard-coded for graph capture.

    const double EPS0 = 1e-9 / 36.0 / M_PI;
    const double MU0  = 4.0 * M_PI * 1e-7;
    const double C0   = 1.0 / sqrt(MU0 * EPS0);
    const double DXd  = 2.5e-8, DYd = 2.5e-8;
    const double DT   = 0.99 / C0 / sqrt(1.0 / (DXd * DXd) + 1.0 / (DYd * DYd));
    const float de_fac = (float)(DT / EPS0);
    const float dh_fac = (float)(DT / MU0);

    // Workspace: [guard row PP] [12 padded fields] [6 padded tables] (~11 MB)
    float* base = (float*)d_ws;
    float* fields = base + PP;
    float* w = fields + 12 * (size_t)FSZ;
    float* dexP = w; w += PP;
    float* deyP = w; w += PP;
    float* aexP = w; w += PP;
    float* aeyP = w; w += PP;
    float* ahxP = w; w += PP;
    float* ahyP = w; w += PP;

    PParams p;
    p.aEz = fields + 0 * (size_t)FSZ;  p.aEo = fields + 1 * (size_t)FSZ;
    p.aJz = fields + 2 * (size_t)FSZ;  p.aJo = fields + 3 * (size_t)FSZ;
    p.aHx = fields + 4 * (size_t)FSZ;  p.aHy = fields + 5 * (size_t)FSZ;
    p.bEz = fields + 6 * (size_t)FSZ;  p.bEo = fields + 7 * (size_t)FSZ;
    p.bJz = fields + 8 * (size_t)FSZ;  p.bJo = fields + 9 * (size_t)FSZ;
    p.bHx = fields + 10 * (size_t)FSZ; p.bHy = fields + 11 * (size_t)FSZ;
    p.dexP = dexP; p.deyP = deyP; p.aexP = aexP; p.aeyP = aeyP;
    p.ahxP = ahxP; p.ahyP = ahyP;
    p.C1a = C1; p.C2a = C2; p.Cbdxa = Cb_dx; p.Cbdya = Cb_dy;
    p.Caa = Ca; p.Cba = Cb; p.Cca = Cc; p.Cda = Cd; p.Cea = Ce;
    p.dbhxa = dbhx; p.dbhya = dbhy;
    p.src = src;

    init_kernel<<<512, 256, 0, stream>>>(sig_ex, sig_ey, sig_hx, sig_hy,
                                         de_fac, dh_fac,
                                         base, PP + 12 * FSZ,
                                         dexP, deyP, aexP, aeyP, ahxP, ahyP);

    dim3 blk(256);
    for (int t = 0; t < NPHASE; ++t) {
        int n0 = Kt * t;
        // Support bound: after n steps the field is confined to a Chebyshev
        // ball of radius n-1 around the source. End of phase t is step 8(t+1)
        // -> radius 8t+7; +8 slack -> R = 8t+15. Launch blocks whose OWNED
        // region [32b+16, 32b+48) intersects [CP-R, CP+R] (conservative;
        // skipped blocks hold exact zeros in both sets; launch sets monotone
        // in t). t-only formula -> identical grids every call (capture-safe).
        int R  = 8 * t + 15;
        int lo = CP - R, hi = CP + R;
        int b0 = (lo - 47) / 32; if (b0 < 0) b0 = 0;
        int b1 = (hi - 16) / 32; if (b1 > NBLK - 1) b1 = NBLK - 1;
        dim3 g(b1 - b0 + 1, b1 - b0 + 1);
        phase_kernel<<<g, blk, 0, stream>>>(p, t, b0, n0);
    }

    // 25 phases starting from set A: t=24 (even) reads A, writes B.
    copy_out_kernel<<<(NXr * NXr + 255) / 256, 256, 0, stream>>>(p.bEz,
                                                                 (float*)d_out);
}

// Round 11
// 286.608 us; speedup vs baseline: 1.1381x; 1.1381x over previous
//
#include <hip/hip_runtime.h>
#include <math.h>

// Real grid (match reference): 421 x 421 E-grid, source at (210,210)
#define NXr 421
#define CXr 210
#define NSTEPS_C 200

// Round 11 = verified Round-6 structure (fastest measured: 299 us) with
// micro-cuts only: copy-out folded into the last phase, tightened support
// slack, one fewer dispatch. Temporal blocking: block = 16x16 threads, each
// thread owns a 2x2 cell quad; EXT=32 tile, Kt=8 steps/phase, owned Bt=16,
// max grid 27x27 = 729 blocks (~2.9/CU late -- the latency-hiding sweet spot;
// R7-R10 measured: deeper tiles / wave-autonomy / grid-sync all worse).
#define Bt   16
#define Kt   8
#define EXT  32
#define SPITCH 34                  // even => float2-aligned LDS rows
#define NBLK 27                    // 27*16 = 432 computational domain
#define NPHASE (NSTEPS_C / Kt)     // 25

// Padded zero-ring layout: fields are PP x PP with the computational domain
// [0,432)^2 at offset (PAD,PAD). Coefficient tables are zero outside the real
// 421^2 domain, so cells outside it provably stay 0 forever -> all hot
// loads/stores are unconditional float2. A zeroed guard row (PP floats) sits
// in front of the field block so ghost loads at padded row/col -1 are safe.
#define PP   448
#define PAD  8
#define CP   (CXr + PAD)           // source in padded coords: 218
#define FSZ  (PP * PP)             // floats per padded field

struct PParams {
    float *aEz, *aEo, *aJz, *aJo, *aHx, *aHy;   // state set A
    float *bEz, *bEo, *bJz, *bJo, *bHx, *bHy;   // state set B
    const float *dexP, *deyP, *aexP, *aeyP, *ahxP, *ahyP;  // padded 1-D tables
    const float *C1a, *C2a, *Cbdxa, *Cbdya;
    const float *Caa, *Cba, *Cca, *Cda, *Cea, *dbhxa, *dbhya;
    const float *src;
};

// ---------------------------------------------------------------------------
// Init: zero guard row + both padded state sets; build padded coeff tables.
// dexP/deyP fold the interior mask (nonzero only for real coords 1..419).
// Zeroing BOTH sets every call keeps the support-gating skip exact.
// ---------------------------------------------------------------------------
__global__ void init_kernel(const float* __restrict__ sig_ex,
                            const float* __restrict__ sig_ey,
                            const float* __restrict__ sig_hx,
                            const float* __restrict__ sig_hy,
                            float de_fac, float dh_fac,
                            float* __restrict__ zero_base, int n_zero,
                            float* __restrict__ dexP, float* __restrict__ deyP,
                            float* __restrict__ aexP, float* __restrict__ aeyP,
                            float* __restrict__ ahxP, float* __restrict__ ahyP)
{
    int t = blockIdx.x * blockDim.x + threadIdx.x;
    int stride = gridDim.x * blockDim.x;
    for (int k = t; k < n_zero; k += stride) zero_base[k] = 0.0f;
    if (t < PP) {
        int g = t - PAD;
        dexP[t] = (g >= 1 && g <= NXr - 2) ? expf(-sig_ex[g] * de_fac) : 0.0f;
        deyP[t] = (g >= 1 && g <= NXr - 2) ? expf(-sig_ey[g] * de_fac) : 0.0f;
        aexP[t] = (g >= 0 && g <  NXr)     ? expf(-sig_ex[g] * dh_fac) : 0.0f;
        aeyP[t] = (g >= 0 && g <  NXr)     ? expf(-sig_ey[g] * dh_fac) : 0.0f;
        ahxP[t] = (g >= 0 && g <  NXr - 1) ? expf(-sig_hx[g] * dh_fac) : 0.0f;
        ahyP[t] = (g >= 0 && g <  NXr - 1) ? expf(-sig_hy[g] * dh_fac) : 0.0f;
    }
}

// ---------------------------------------------------------------------------
// One temporal-blocked phase (Kt=8 steps), ONE barrier per step.
// Ez is the only field exchanged through LDS (parity-double-buffered tile:
// step s+1 stores to the other buffer, so the single barrier is WAR-safe).
// Up/left neighbor H values are ghost registers updated redundantly from the
// exchanged Ez (identical arithmetic to the neighbor's own update).
// writeOut: last phase also writes its owned Ez directly to the dense output
// (owned regions tile the domain exactly) -- replaces the copy_out dispatch.
// ---------------------------------------------------------------------------
__global__ __launch_bounds__(256)
void phase_kernel(PParams p, int t, int b0, float* __restrict__ out,
                  int writeOut)
{
    __shared__ __align__(16) float sEz[2][EXT][SPITCH];

    const int tid = threadIdx.x;
    const int tj = tid & 15, ti = tid >> 4;
    const int li0 = 2 * ti, lj0 = 2 * tj;
    const int r0 = ((int)blockIdx.x + b0) * Bt + li0;  // padded row, cell(0,*)
    const int c0 = ((int)blockIdx.y + b0) * Bt + lj0;  // padded col, cell(*,0)

    const float ca = p.Caa[0], cb = p.Cba[0], cc = p.Cca[0];
    const float cd = p.Cda[0], ce = p.Cea[0];
    const float ca1 = ca + 1.0f;
    const float C1 = p.C1a[0], C2 = p.C2a[0];
    const float cbdx = p.Cbdxa[0], cbdy = p.Cbdya[0];
    const float dbhx0 = p.dbhxa[0], dbhy0 = p.dbhya[0];

    // Per-cell damping products (interior mask folded into dE) + ghost damping
    float dHx[2][2], dHy[2][2], dE[2][2], dHyU[2], dHxL[2];
    bool isSrc[2][2];
#pragma unroll
    for (int a = 0; a < 2; ++a)
#pragma unroll
        for (int b = 0; b < 2; ++b) {
            dHx[a][b] = p.aexP[r0 + a] * p.ahyP[c0 + b];
            dHy[a][b] = p.ahxP[r0 + a] * p.aeyP[c0 + b];
            dE[a][b]  = p.dexP[r0 + a] * p.deyP[c0 + b];
            isSrc[a][b] = (r0 + a == CP) && (c0 + b == CP);
        }
    {
        float ahxU = (r0 > 0) ? p.ahxP[r0 - 1] : 0.0f;   // table idx guard
        float ahyL = (c0 > 0) ? p.ahyP[c0 - 1] : 0.0f;
        dHyU[0] = ahxU * p.aeyP[c0];
        dHyU[1] = ahxU * p.aeyP[c0 + 1];
        dHxL[0] = p.aexP[r0] * ahyL;
        dHxL[1] = p.aexP[r0 + 1] * ahyL;
    }

    const bool odd = (t & 1) != 0;
    const float* cEz = odd ? p.bEz : p.aEz;
    const float* cEo = odd ? p.bEo : p.aEo;
    const float* cJz = odd ? p.bJz : p.aJz;
    const float* cJo = odd ? p.bJo : p.aJo;
    const float* cHx = odd ? p.bHx : p.aHx;
    const float* cHy = odd ? p.bHy : p.aHy;
    float* nEz = odd ? p.aEz : p.bEz;
    float* nEo = odd ? p.aEo : p.bEo;
    float* nJz = odd ? p.aJz : p.bJz;
    float* nJo = odd ? p.aJo : p.bJo;
    float* nHx = odd ? p.aHx : p.bHx;
    float* nHy = odd ? p.aHy : p.bHy;

    // Load 2x2 register state (unconditional padded float2)
    float ez[2][2], eo[2][2], jz[2][2], jo[2][2], hx[2][2], hy[2][2];
#pragma unroll
    for (int a = 0; a < 2; ++a) {
        int g = (r0 + a) * PP + c0;
        float2 v;
        v = *(const float2*)&cEz[g]; ez[a][0] = v.x; ez[a][1] = v.y;
        v = *(const float2*)&cEo[g]; eo[a][0] = v.x; eo[a][1] = v.y;
        v = *(const float2*)&cJz[g]; jz[a][0] = v.x; jz[a][1] = v.y;
        v = *(const float2*)&cJo[g]; jo[a][0] = v.x; jo[a][1] = v.y;
        v = *(const float2*)&cHx[g]; hx[a][0] = v.x; hx[a][1] = v.y;
        v = *(const float2*)&cHy[g]; hy[a][0] = v.x; hy[a][1] = v.y;
    }
    // Ghost H (row above / col left); guard row + zero pads make -1 safe
    float hyU[2], hxL[2];
    {
        float2 v = *(const float2*)&cHy[(r0 - 1) * PP + c0];
        hyU[0] = v.x; hyU[1] = v.y;
        hxL[0] = cHx[r0 * PP + c0 - 1];
        hxL[1] = cHx[(r0 + 1) * PP + c0 - 1];
    }

    const bool edgeR = (tj == 15), edgeD = (ti == 15);
    const bool edgeU = (ti == 0),  edgeL = (tj == 0);
    const int n0 = t * Kt;

    for (int s = 0; s < Kt; ++s) {
        float (*S)[SPITCH] = sEz[s & 1];
        // publish all 4 Ez cells
        *(float2*)&S[li0][lj0]     = make_float2(ez[0][0], ez[0][1]);
        *(float2*)&S[li0 + 1][lj0] = make_float2(ez[1][0], ez[1][1]);
        __syncthreads();

        float eR0 = edgeR ? 0.0f : S[li0][lj0 + 2];
        float eR1 = edgeR ? 0.0f : S[li0 + 1][lj0 + 2];
        float2 eD  = edgeD ? make_float2(0.0f, 0.0f)
                           : *(float2*)&S[li0 + 2][lj0];
        float2 eU  = edgeU ? make_float2(0.0f, 0.0f)
                           : *(float2*)&S[li0 - 1][lj0];
        float eL0 = edgeL ? 0.0f : S[li0][lj0 - 1];
        float eL1 = edgeL ? 0.0f : S[li0 + 1][lj0 - 1];

        // ---- H update (own 2x2) ----
        hx[0][0] = dHx[0][0] * (hx[0][0] - dbhx0 * (ez[0][1] - ez[0][0]));
        hx[0][1] = dHx[0][1] * (hx[0][1] - dbhx0 * (eR0     - ez[0][1]));
        hx[1][0] = dHx[1][0] * (hx[1][0] - dbhx0 * (ez[1][1] - ez[1][0]));
        hx[1][1] = dHx[1][1] * (hx[1][1] - dbhx0 * (eR1     - ez[1][1]));

        hy[0][0] = dHy[0][0] * (hy[0][0] + dbhy0 * (ez[1][0] - ez[0][0]));
        hy[0][1] = dHy[0][1] * (hy[0][1] + dbhy0 * (ez[1][1] - ez[0][1]));
        hy[1][0] = dHy[1][0] * (hy[1][0] + dbhy0 * (eD.x     - ez[1][0]));
        hy[1][1] = dHy[1][1] * (hy[1][1] + dbhy0 * (eD.y     - ez[1][1]));

        // ---- ghost H update (same arithmetic as the neighbor's own) ----
        hyU[0] = dHyU[0] * (hyU[0] + dbhy0 * (ez[0][0] - eU.x));
        hyU[1] = dHyU[1] * (hyU[1] + dbhy0 * (ez[0][1] - eU.y));
        hxL[0] = dHxL[0] * (hxL[0] - dbhx0 * (ez[0][0] - eL0));
        hxL[1] = dHxL[1] * (hxL[1] - dbhx0 * (ez[1][0] - eL1));

        // ---- E update (all operands in registers) ----
        float sv = p.src[n0 + s];
        float cHyv[2][2], cHxv[2][2];
        cHyv[0][0] = hy[0][0] - hyU[0];   cHxv[0][0] = hx[0][0] - hxL[0];
        cHyv[0][1] = hy[0][1] - hyU[1];   cHxv[0][1] = hx[0][1] - hx[0][0];
        cHyv[1][0] = hy[1][0] - hy[0][0]; cHxv[1][0] = hx[1][0] - hxL[1];
        cHyv[1][1] = hy[1][1] - hy[0][1]; cHxv[1][1] = hx[1][1] - hx[1][0];

#pragma unroll
        for (int a = 0; a < 2; ++a)
#pragma unroll
            for (int b = 0; b < 2; ++b) {
                float e = ez[a][b], eold = eo[a][b];
                float j = jz[a][b], jold = jo[a][b];
                float phi = ca1 * j + cb * jold + cd * e + ce * eold;
                float en = dE[a][b] *
                    (C1 * e + cbdx * cHyv[a][b] - cbdy * cHxv[a][b] - C2 * phi);
                if (isSrc[a][b]) en += sv;      // source after mask*de
                float jn = phi - j + cc * en;   // == ca*j+cb*jo+cc*en+cd*e+ce*eo
                eo[a][b] = e;  ez[a][b] = en;
                jo[a][b] = j;  jz[a][b] = jn;
            }
        // Single barrier per step: next iteration stores to the OTHER LDS
        // buffer (parity), so late readers of this buffer are safe (R5/R6).
    }

    // store owned interior [Kt, Kt+Bt)^2 -> ti,tj in [4,12)
    if (ti >= 4 && ti < 12 && tj >= 4 && tj < 12) {
#pragma unroll
        for (int a = 0; a < 2; ++a) {
            int g = (r0 + a) * PP + c0;
            *(float2*)&nEz[g] = make_float2(ez[a][0], ez[a][1]);
            *(float2*)&nEo[g] = make_float2(eo[a][0], eo[a][1]);
            *(float2*)&nJz[g] = make_float2(jz[a][0], jz[a][1]);
            *(float2*)&nJo[g] = make_float2(jo[a][0], jo[a][1]);
            *(float2*)&nHx[g] = make_float2(hx[a][0], hx[a][1]);
            *(float2*)&nHy[g] = make_float2(hy[a][0], hy[a][1]);
        }
        // Last phase: owned regions tile the padded domain exactly; emit the
        // dense 421x421 output directly (same register values copy_out read).
        if (writeOut) {
#pragma unroll
            for (int a = 0; a < 2; ++a)
#pragma unroll
                for (int b = 0; b < 2; ++b) {
                    int gi = r0 + a - PAD, gj = c0 + b - PAD;  // >= 0 (owned)
                    if (gi < NXr && gj < NXr)
                        out[gi * NXr + gj] = ez[a][b];
                }
        }
    }
}

// ---------------------------------------------------------------------------
extern "C" void kernel_launch(void* const* d_in, const int* in_sizes, int n_in,
                              void* d_out, int out_size, void* d_ws, size_t ws_size,
                              hipStream_t stream)
{
    const float* src    = (const float*)d_in[0];
    const float* C1     = (const float*)d_in[1];
    const float* C2     = (const float*)d_in[2];
    const float* Cb_dx  = (const float*)d_in[3];
    const float* Cb_dy  = (const float*)d_in[4];
    const float* dbhx   = (const float*)d_in[5];
    const float* dbhy   = (const float*)d_in[6];
    const float* Ca     = (const float*)d_in[7];
    const float* Cb     = (const float*)d_in[8];
    const float* Cc     = (const float*)d_in[9];
    const float* Cd     = (const float*)d_in[10];
    const float* Ce     = (const float*)d_in[11];
    const float* sig_ex = (const float*)d_in[12];
    const float* sig_ey = (const float*)d_in[13];
    const float* sig_hx = (const float*)d_in[14];
    const float* sig_hy = (const float*)d_in[15];
    // d_in[16] = n_steps (always 200) — hard-coded for graph capture.

    const double EPS0 = 1e-9 / 36.0 / M_PI;
    const double MU0  = 4.0 * M_PI * 1e-7;
    const double C0   = 1.0 / sqrt(MU0 * EPS0);
    const double DXd  = 2.5e-8, DYd = 2.5e-8;
    const double DT   = 0.99 / C0 / sqrt(1.0 / (DXd * DXd) + 1.0 / (DYd * DYd));
    const float de_fac = (float)(DT / EPS0);
    const float dh_fac = (float)(DT / MU0);

    // Workspace: [guard row PP] [12 padded fields] [6 padded tables] (~10 MB)
    float* base = (float*)d_ws;
    float* fields = base + PP;
    float* w = fields + 12 * (size_t)FSZ;
    float* dexP = w; w += PP;
    float* deyP = w; w += PP;
    float* aexP = w; w += PP;
    float* aeyP = w; w += PP;
    float* ahxP = w; w += PP;
    float* ahyP = w; w += PP;

    PParams p;
    p.aEz = fields + 0 * (size_t)FSZ;  p.aEo = fields + 1 * (size_t)FSZ;
    p.aJz = fields + 2 * (size_t)FSZ;  p.aJo = fields + 3 * (size_t)FSZ;
    p.aHx = fields + 4 * (size_t)FSZ;  p.aHy = fields + 5 * (size_t)FSZ;
    p.bEz = fields + 6 * (size_t)FSZ;  p.bEo = fields + 7 * (size_t)FSZ;
    p.bJz = fields + 8 * (size_t)FSZ;  p.bJo = fields + 9 * (size_t)FSZ;
    p.bHx = fields + 10 * (size_t)FSZ; p.bHy = fields + 11 * (size_t)FSZ;
    p.dexP = dexP; p.deyP = deyP; p.aexP = aexP; p.aeyP = aeyP;
    p.ahxP = ahxP; p.ahyP = ahyP;
    p.C1a = C1; p.C2a = C2; p.Cbdxa = Cb_dx; p.Cbdya = Cb_dy;
    p.Caa = Ca; p.Cba = Cb; p.Cca = Cc; p.Cda = Cd; p.Cea = Ce;
    p.dbhxa = dbhx; p.dbhya = dbhy;
    p.src = src;

    init_kernel<<<512, 256, 0, stream>>>(sig_ex, sig_ey, sig_hx, sig_hy,
                                         de_fac, dh_fac,
                                         base, PP + 12 * FSZ,
                                         dexP, deyP, aexP, aeyP, ahxP, ahyP);

    dim3 blk(256);
    for (int t = 0; t < NPHASE; ++t) {
        // Support bound: after n steps the field is confined to a Chebyshev
        // ball of radius n-1 around the source. End of phase t is step 8(t+1)
        // -> radius 8t+7. Tile-based gate with R = 8t+11 has >= +10 margin
        // over the owned-region criterion (derivation in journal; R6 used
        // 8t+15). Launch sets are monotone in t -> the ping-pong skip stays
        // exact. t-only formula -> identical grids every call (capture-safe).
        int R  = 8 * t + 11;
        int lo = CP - R, hi = CP + R;
        int b0 = (lo - (EXT - 1)) / 16; if (b0 < 0) b0 = 0;
        int b1 = hi / 16;               if (b1 > NBLK - 1) b1 = NBLK - 1;
        dim3 g(b1 - b0 + 1, b1 - b0 + 1);
        phase_kernel<<<g, blk, 0, stream>>>(p, t, b0, (float*)d_out,
                                            (t == NPHASE - 1) ? 1 : 0);
    }
    // No copy_out dispatch: phase t=24 wrote the dense output directly.
}